// Round 10
// baseline (209.336 us; speedup 1.0000x reference)
//
#include <hip/hip_runtime.h>

// KerasCustomMappingLayer: B=32768 rows x H=512 sequential steps, out (B,H,6) f32.
//
// R10 = R9 (wave-per-row, A/B/C phase split, minimal traffic) +
//  (1) BALANCED phase-B: segments tile each 256-step half contiguously, so
//      prefix-length == seg_start - kb. Lane i owns all segments STARTING in
//      [kb+4i, kb+4i+4)  => wave B-time = max lane total ~ longest_seg+4 (~22)
//      instead of sum-of-slot-maxes (~48). Carry across the half boundary is
//      handed off through LDS (bd_hx/hy), written by the unique lane whose
//      last segment was clipped.
//  (2) WAVE-LOCAL sync: bd_* arrays are per-wave; the block-wide syncthreads
//      between A/B/C phases are replaced by s_waitcnt lgkmcnt(0) (wave is
//      lockstep => all lanes' LDS writes are complete & visible after the
//      wait). Only the two initial barriers (s_lk staging, seg_list build)
//      remain block-wide. Waves no longer stall on each other's phase skew.
// Numerics: carry path bit-identical to numpy fp32 (contract off, IEEE
// div/sqrt, per-step rr = lk>192); outputs use *1/512 (pow2-exact) and
// *1/384 mul (<=1ulp, output-only) - proven R8/R9: absmax 0.0078 unchanged.
// Frozen lessons: plain stores (R2-NT, R4-ragged both amplified writes ~2x);
// dense per-phase global access (R1); no VGPR squeeze (R5).

#define H 512
#define RPB 4      // rows per block = waves per block
#define HALF 256   // k-steps staged per phase

typedef float v2f __attribute__((ext_vector_type(2)));

#define WFENCE() do { \
    asm volatile("s_waitcnt lgkmcnt(0)" ::: "memory"); \
    __builtin_amdgcn_sched_barrier(0); \
} while (0)

__device__ __forceinline__ int lbound(const int* __restrict__ a, int n, int val) {
    int lo = 0, hi = n;
    while (lo < hi) { int m = (lo + hi) >> 1; if (a[m] < val) lo = m + 1; else hi = m; }
    return lo;
}

__global__ __launch_bounds__(256, 4)
void construct_map_seg(const float* __restrict__ mapvars,
                       const float* __restrict__ rel,
                       const float* __restrict__ start_pos,
                       const float* __restrict__ lmul,
                       const int* __restrict__ nfse_p,
                       float* __restrict__ out)
{
#pragma clang fp contract(off)
    __shared__ float s_lk[H];
    __shared__ float s_issl[H];
    __shared__ int   seg_list[H + 8];
    __shared__ int   nseg_s;
    __shared__ float bd_dx[RPB][HALF];
    __shared__ float bd_dy[RPB][HALF];
    __shared__ float bd_e1[RPB][HALF];
    __shared__ float bd_e2[RPB][HALF];
    __shared__ float bd_rx[RPB][HALF];
    __shared__ float bd_ry[RPB][HALF];
    __shared__ float bd_xx[RPB][HALF];
    __shared__ float bd_yy[RPB][HALF];
    __shared__ float bd_hx[RPB];
    __shared__ float bd_hy[RPB];

    const int tid = threadIdx.x;
    const int w = tid >> 6;
    const int lane = tid & 63;
    const int row = blockIdx.x * RPB + w;

    const float lm = lmul[0];
    for (int i = tid; i < H; i += 256) {
        s_lk[i] = __fmul_rn(lm, rel[5 * H + i]);   // l = lmul * note_dist
        s_issl[i] = rel[i];                        // is_slider
    }
    __syncthreads();

    // segment list: starts = {0} U {k : l[k] > 192}  (k-only, all rows share)
    if (tid < 64) {
        int base = 0;
        for (int c = 0; c < H / 64; ++c) {
            int k = c * 64 + tid;
            bool isr = (k == 0) || (s_lk[k] > 192.0f);
            unsigned long long m = __ballot(isr);
            int idx = base + __popcll(m & ((1ull << tid) - 1ull));
            if (isr) seg_list[idx] = k;
            base += __popcll(m);
        }
        if (tid == 0) { seg_list[base] = H; nseg_s = base; }
    }
    __syncthreads();

    const int nseg = nseg_s;
    const bool nfse = (nfse_p[0] != 0);
    const float sx = start_pos[0], sy = start_pos[1];

    const float WL = (float)(0.05 * 512.0);
    const float WR = (float)(0.95 * 512.0);
    const float WT = (float)(0.05 * 384.0);
    const float WB = (float)(0.95 * 384.0);

    const float* rowp = mapvars + (size_t)row * (4 * H);
    float* orow = out + (size_t)row * (H * 6);

    for (int h = 0; h < 2; ++h) {
        const int kb = h * HALF;
        const int kend = kb + HALF;
        float o2r[4], o3r[4], e1r[4], e2r[4];

        // ---- A: heavy per-k math, dense, all lanes active ----
#pragma unroll
        for (int j = 0; j < 4; ++j) {
            const int kk = lane + 64 * j;
            const int k = kb + kk;
            float m0 = rowp[k];
            float m1 = rowp[H + k];
            float m2 = rowp[2 * H + k];
            float m3 = rowp[3 * H + k];
            float sln  = rel[H + k];
            float scos = rel[3 * H + k];
            float ssin = rel[4 * H + k];
            float lk  = s_lk[k];
            float isf = s_issl[k];

            float len1 = __fsqrt_rn(__fadd_rn(__fmul_rn(m0, m0), __fmul_rn(m2, m2)));
            float ck = __fdiv_rn(m0, len1);
            float sk = __fdiv_rn(m2, len1);
            float len2 = __fsqrt_rn(__fadd_rn(__fmul_rn(m1, m1), __fmul_rn(m3, m3)));
            float ck2 = __fdiv_rn(m1, len2);
            float sk2 = __fdiv_rn(m3, len2);

            float dx = __fmul_rn(lk, ck);
            float dy = __fmul_rn(lk, sk);
            float rx = __fadd_rn(256.0f, __fmul_rn(256.0f, m0));
            float ry = __fadd_rn(192.0f, __fmul_rn(192.0f, m2));
            float e1 = __fmul_rn(ck2, sln);
            float e2 = __fmul_rn(sk2, sln);
            bool rr  = lk > 192.0f;
            bool isl = isf != 0.0f;
            float oa = __fadd_rn(__fmul_rn(ck2, scos), -__fmul_rn(sk2, ssin));
            float ob = __fadd_rn(__fmul_rn(ck2, ssin),  __fmul_rn(sk2, scos));
            o2r[j] = isl ? oa : (rr ? ck2 : ck);
            o3r[j] = isl ? ob : (rr ? sk2 : sk);
            e1r[j] = e1; e2r[j] = e2;
            bd_dx[w][kk] = dx; bd_dy[w][kk] = dy;
            bd_e1[w][kk] = e1; bd_e2[w][kk] = e2;
            bd_rx[w][kk] = rx; bd_ry[w][kk] = ry;
        }
        WFENCE();   // wave-local: A's LDS writes visible to all lanes of this wave

        // ---- B: serial carry chain, balanced by segment START position ----
        {
            const int nv = nseg + 1;                       // seg_list entries incl sentinel
            int S = lbound(seg_list, nv, kb + 1) - 1;      // first active sid
            if (S < 0) S = 0;
            const int myfirst = (lane == 0) ? S : lbound(seg_list, nv, kb + 4 * lane);
            const int mylast  = lbound(seg_list, nv, kb + 4 * (lane + 1));

            if (myfirst < mylast) {
                int sid = myfirst;
                int k  = seg_list[sid];
                int hi = seg_list[sid + 1];
                float px = 0.0f, py = 0.0f;
                if (k == 0)      { px = sx;        py = sy; }
                else if (k < kb) { px = bd_hx[w];  py = bd_hy[w]; }   // half-crossing
                if (k < kb)   k = kb;
                if (hi > kend) hi = kend;
                while (true) {
                    const int kk = k - kb;
                    float lk = s_lk[k];
                    float _x, _y;
                    if (lk > 192.0f) {            // rerand (only at segment heads)
                        _x = bd_rx[w][kk];
                        _y = bd_ry[w][kk];
                    } else {
                        float hl = __fmul_rn(lk, 0.5f);
                        float wl = __fadd_rn(WL, hl);
                        float wr = __fadd_rn(WR, -hl);
                        float wt = __fadd_rn(WT, hl);
                        float wb = __fadd_rn(WB, -hl);
                        float dx = bd_dx[w][kk], dy = bd_dy[w][kk];
                        float adx = fabsf(dx), ady = fabsf(dy);
                        float xd = (px < wl) ? adx : ((px > wr) ? -adx : (((px > wl) && (px < wr)) ? dx : 0.0f));
                        float yd = (py < wt) ? ady : ((py > wb) ? -ady : (((py > wt) && (py < wb)) ? dy : 0.0f));
                        _x = __fadd_rn(px, xd);
                        _y = __fadd_rn(py, yd);
                    }
                    bd_xx[w][kk] = _x;
                    bd_yy[w][kk] = _y;
                    if ((s_issl[k] != 0.0f) && nfse) {
                        px = __fadd_rn(_x, bd_e1[w][kk]);
                        py = __fadd_rn(_y, bd_e2[w][kk]);
                    } else { px = _x; py = _y; }
                    ++k;
                    if (k >= hi) {
                        ++sid;
                        if (sid >= mylast) break;
                        k = seg_list[sid];                 // fresh head: > kb, no clip
                        hi = seg_list[sid + 1];
                        if (hi > kend) hi = kend;
                        px = 0.0f; py = 0.0f;              // head has lk>192: carry dead
                    }
                }
                // unique clipped-last-segment lane hands carry to next half
                if (h == 0 && seg_list[mylast] > kend) { bd_hx[w] = px; bd_hy[w] = py; }
            }
        }
        WFENCE();   // B's bd_xx/yy (+handoff) visible wave-wide

        // ---- C: output assembly, dense stores ----
#pragma unroll
        for (int j = 0; j < 4; ++j) {
            const int kk = lane + 64 * j;
            const int k = kb + kk;
            float _x = bd_xx[w][kk], _y = bd_yy[w][kk];
            float o0 = __fmul_rn(_x, 1.0f / 512.0f);
            float o1 = __fmul_rn(_y, 1.0f / 384.0f);
            bool isl = s_issl[k] != 0.0f;
            float o4 = o0, o5 = o1;
            if (isl) {
                o4 = __fmul_rn(__fadd_rn(_x, e1r[j]), 1.0f / 512.0f);
                o5 = __fmul_rn(__fadd_rn(_y, e2r[j]), 1.0f / 384.0f);
            }
            float* op = orow + (size_t)k * 6;
            v2f a = {o0, o1};
            v2f b = {o2r[j], o3r[j]};
            v2f c = {o4, o5};
            *(v2f*)(op)     = a;
            *(v2f*)(op + 2) = b;
            *(v2f*)(op + 4) = c;
        }
        WFENCE();   // C's reads of bd_xx/yy done before next half's A overwrites
    }
}

extern "C" void kernel_launch(void* const* d_in, const int* in_sizes, int n_in,
                              void* d_out, int out_size, void* d_ws, size_t ws_size,
                              hipStream_t stream) {
    const float* mapvars = (const float*)d_in[0];
    const float* rel     = (const float*)d_in[1];
    const float* sp      = (const float*)d_in[2];
    const float* lm      = (const float*)d_in[3];
    const int*   nfse    = (const int*)d_in[4];
    float* out = (float*)d_out;

    const int B = in_sizes[0] / (4 * H);   // 32768
    hipLaunchKernelGGL(construct_map_seg, dim3(B / RPB), dim3(256), 0, stream,
                       mapvars, rel, sp, lm, nfse, out);
}

// Round 11
// 184.494 us; speedup vs baseline: 1.1347x; 1.1347x over previous
//
#include <hip/hip_runtime.h>

// KerasCustomMappingLayer: B=32768 rows x H=512 sequential steps, out (B,H,6) f32.
//
// R11 = R9 (proven 193us: wave-per-row, A/B/C phases, slot-B, __syncthreads)
// with ONE change: phase-B LDS traffic packed & branch-folded.
//   - bd_d{dx,dy}, bd_r{rx,ry}, bd_a{e1c,e2c}, bd_xy{_x,_y} as float2 (b64 ops)
//   - e1c = (is_slider && nfse) ? ck2*slider_len : 0 computed in A, so B's
//     carry advance is UNCONDITIONAL px=_x+e1c (+0.0 add is bit-safe: the
//     -0+0->+0 edge cannot change any comparison, add, or |output| diff).
//   - B no longer reads s_issl and has no slider branch: 4-5 LDS ops/step
//     (was ~8-9 scalar ops). Serial chain is LDS-op-bound -> direct cut.
// R10 lesson: single-axis changes only; balanced-B + wave fences bundled a
// regression (193->209) that couldn't be attributed. Slot-B + syncthreads kept.
// Numerics: carry path bit-identical to numpy fp32 (contract off, IEEE
// div/sqrt, per-step rr = lk>192); outputs *1/512 pow2-exact, *1/384 <=1ulp
// output-only (absmax 0.0078 stable R8-R10).
// Frozen: plain stores (R2/R4: NT and ragged scalar stores amplify writes 2x+),
// dense per-phase global access (R1), no VGPR squeeze (R5).

#define H 512
#define RPB 4      // rows per block = waves per block
#define HALF 256   // k-steps staged per phase

typedef float v2f __attribute__((ext_vector_type(2)));

__global__ __launch_bounds__(256, 4)
void construct_map_seg(const float* __restrict__ mapvars,
                       const float* __restrict__ rel,
                       const float* __restrict__ start_pos,
                       const float* __restrict__ lmul,
                       const int* __restrict__ nfse_p,
                       float* __restrict__ out)
{
#pragma clang fp contract(off)
    __shared__ float s_lk[H];
    __shared__ float s_issl[H];
    __shared__ int   seg_list[H + 8];
    __shared__ int   nseg_s;
    __shared__ float2 bd_d [RPB][HALF];   // {dx, dy}
    __shared__ float2 bd_r [RPB][HALF];   // {rerand_x, rerand_y}
    __shared__ float2 bd_a [RPB][HALF];   // {e1c, e2c} advance (0 if not slider&&nfse)
    __shared__ float2 bd_xy[RPB][HALF];   // {_x, _y} result

    const int tid = threadIdx.x;
    const int w = tid >> 6;
    const int lane = tid & 63;
    const int row = blockIdx.x * RPB + w;

    const float lm = lmul[0];
    for (int i = tid; i < H; i += 256) {
        s_lk[i] = __fmul_rn(lm, rel[5 * H + i]);   // l = lmul * note_dist
        s_issl[i] = rel[i];                        // is_slider
    }
    __syncthreads();

    // segment list: starts = {0} U {k : l[k] > 192}  (k-only, all rows share)
    if (tid < 64) {
        int base = 0;
        for (int c = 0; c < H / 64; ++c) {
            int k = c * 64 + tid;
            bool isr = (k == 0) || (s_lk[k] > 192.0f);
            unsigned long long m = __ballot(isr);
            int idx = base + __popcll(m & ((1ull << tid) - 1ull));
            if (isr) seg_list[idx] = k;
            base += __popcll(m);
        }
        if (tid == 0) { seg_list[base] = H; nseg_s = base; }
    }
    __syncthreads();

    const int nseg = nseg_s;
    const bool nfse = (nfse_p[0] != 0);
    const float sx = start_pos[0], sy = start_pos[1];

    const float WL = (float)(0.05 * 512.0);
    const float WR = (float)(0.95 * 512.0);
    const float WT = (float)(0.05 * 384.0);
    const float WB = (float)(0.95 * 384.0);

    const float* rowp = mapvars + (size_t)row * (4 * H);
    float* orow = out + (size_t)row * (H * 6);

    float pxs0 = 0.f, pys0 = 0.f, pxs1 = 0.f, pys1 = 0.f;
    float pxs2 = 0.f, pys2 = 0.f, pxs3 = 0.f, pys3 = 0.f;

    for (int h = 0; h < 2; ++h) {
        const int kb = h * HALF;
        float o2r[4], o3r[4], e1r[4], e2r[4];

        // ---- A: heavy per-k math, dense, all lanes active ----
#pragma unroll
        for (int j = 0; j < 4; ++j) {
            const int kk = lane + 64 * j;
            const int k = kb + kk;
            float m0 = rowp[k];
            float m1 = rowp[H + k];
            float m2 = rowp[2 * H + k];
            float m3 = rowp[3 * H + k];
            float sln  = rel[H + k];
            float scos = rel[3 * H + k];
            float ssin = rel[4 * H + k];
            float lk  = s_lk[k];
            float isf = s_issl[k];

            float len1 = __fsqrt_rn(__fadd_rn(__fmul_rn(m0, m0), __fmul_rn(m2, m2)));
            float ck = __fdiv_rn(m0, len1);
            float sk = __fdiv_rn(m2, len1);
            float len2 = __fsqrt_rn(__fadd_rn(__fmul_rn(m1, m1), __fmul_rn(m3, m3)));
            float ck2 = __fdiv_rn(m1, len2);
            float sk2 = __fdiv_rn(m3, len2);

            float dx = __fmul_rn(lk, ck);
            float dy = __fmul_rn(lk, sk);
            float rx = __fadd_rn(256.0f, __fmul_rn(256.0f, m0));
            float ry = __fadd_rn(192.0f, __fmul_rn(192.0f, m2));
            float e1 = __fmul_rn(ck2, sln);
            float e2 = __fmul_rn(sk2, sln);
            bool rr  = lk > 192.0f;
            bool isl = isf != 0.0f;
            float oa = __fadd_rn(__fmul_rn(ck2, scos), -__fmul_rn(sk2, ssin));
            float ob = __fadd_rn(__fmul_rn(ck2, ssin),  __fmul_rn(sk2, scos));
            o2r[j] = isl ? oa : (rr ? ck2 : ck);
            o3r[j] = isl ? ob : (rr ? sk2 : sk);
            e1r[j] = e1; e2r[j] = e2;

            v2f d2 = {dx, dy};
            v2f r2 = {rx, ry};
            bool adv = isl && nfse;
            v2f a2 = {adv ? e1 : 0.0f, adv ? e2 : 0.0f};
            *(v2f*)&bd_d[w][kk] = d2;
            *(v2f*)&bd_r[w][kk] = r2;
            *(v2f*)&bd_a[w][kk] = a2;
        }
        __syncthreads();

        // ---- B: serial carry chain, slot-parallel (R9 structure) ----
#pragma unroll
        for (int slot = 0; slot < 4; ++slot) {
            const int sid = lane + 64 * slot;
            if (sid < nseg) {
                const int k0 = seg_list[sid];
                const int k1 = seg_list[sid + 1];
                const int lo = (k0 > kb) ? k0 : kb;
                const int hi = (k1 < kb + HALF) ? k1 : (kb + HALF);
                float px, py;
                if (k0 >= kb) {              // segment starts in this half
                    px = (k0 == 0) ? sx : 0.0f;
                    py = (k0 == 0) ? sy : 0.0f;
                } else {                     // continues from previous half
                    px = (slot == 0) ? pxs0 : (slot == 1) ? pxs1 : (slot == 2) ? pxs2 : pxs3;
                    py = (slot == 0) ? pys0 : (slot == 1) ? pys1 : (slot == 2) ? pys2 : pys3;
                }
                for (int k = lo; k < hi; ++k) {
                    const int kk = k - kb;
                    float lk = s_lk[k];
                    float _x, _y;
                    if (lk > 192.0f) {       // rerand: carry-independent
                        float2 r2 = bd_r[w][kk];
                        _x = r2.x;
                        _y = r2.y;
                    } else {
                        float2 d2 = bd_d[w][kk];
                        float hl = __fmul_rn(lk, 0.5f);
                        float wl = __fadd_rn(WL, hl);
                        float wr = __fadd_rn(WR, -hl);
                        float wt = __fadd_rn(WT, hl);
                        float wb = __fadd_rn(WB, -hl);
                        float dx = d2.x, dy = d2.y;
                        float adx = fabsf(dx), ady = fabsf(dy);
                        float xd = (px < wl) ? adx : ((px > wr) ? -adx : (((px > wl) && (px < wr)) ? dx : 0.0f));
                        float yd = (py < wt) ? ady : ((py > wb) ? -ady : (((py > wt) && (py < wb)) ? dy : 0.0f));
                        _x = __fadd_rn(px, xd);
                        _y = __fadd_rn(py, yd);
                    }
                    v2f xy = {_x, _y};
                    *(v2f*)&bd_xy[w][kk] = xy;
                    float2 a2 = bd_a[w][kk];     // {0,0} unless slider && nfse
                    px = __fadd_rn(_x, a2.x);    // +0.0 bit-safe (see header)
                    py = __fadd_rn(_y, a2.y);
                }
                if (slot == 0) { pxs0 = px; pys0 = py; }
                else if (slot == 1) { pxs1 = px; pys1 = py; }
                else if (slot == 2) { pxs2 = px; pys2 = py; }
                else { pxs3 = px; pys3 = py; }
            }
        }
        __syncthreads();

        // ---- C: output assembly, dense stores ----
#pragma unroll
        for (int j = 0; j < 4; ++j) {
            const int kk = lane + 64 * j;
            const int k = kb + kk;
            float2 xy = bd_xy[w][kk];
            float _x = xy.x, _y = xy.y;
            float o0 = __fmul_rn(_x, 1.0f / 512.0f);
            float o1 = __fmul_rn(_y, 1.0f / 384.0f);
            bool isl = s_issl[k] != 0.0f;
            float o4 = o0, o5 = o1;
            if (isl) {
                o4 = __fmul_rn(__fadd_rn(_x, e1r[j]), 1.0f / 512.0f);
                o5 = __fmul_rn(__fadd_rn(_y, e2r[j]), 1.0f / 384.0f);
            }
            float* op = orow + (size_t)k * 6;
            v2f a = {o0, o1};
            v2f b = {o2r[j], o3r[j]};
            v2f c = {o4, o5};
            *(v2f*)(op)     = a;
            *(v2f*)(op + 2) = b;
            *(v2f*)(op + 4) = c;
        }
        __syncthreads();
    }
}

extern "C" void kernel_launch(void* const* d_in, const int* in_sizes, int n_in,
                              void* d_out, int out_size, void* d_ws, size_t ws_size,
                              hipStream_t stream) {
    const float* mapvars = (const float*)d_in[0];
    const float* rel     = (const float*)d_in[1];
    const float* sp      = (const float*)d_in[2];
    const float* lm      = (const float*)d_in[3];
    const int*   nfse    = (const int*)d_in[4];
    float* out = (float*)d_out;

    const int B = in_sizes[0] / (4 * H);   // 32768
    hipLaunchKernelGGL(construct_map_seg, dim3(B / RPB), dim3(256), 0, stream,
                       mapvars, rel, sp, lm, nfse, out);
}

// Round 12
// 173.656 us; speedup vs baseline: 1.2055x; 1.0624x over previous
//
#include <hip/hip_runtime.h>

// KerasCustomMappingLayer: B=32768 rows x H=512 sequential steps, out (B,H,6) f32.
//
// R12 = R11 (proven 184.5us) with ONE change: HALF 256 -> 128.
//   LDS/block 38.6KB -> ~22.6KB  =>  4 -> 7 blocks/CU (16 -> 28 waves/CU).
//   B's dependent carry chain (~30cy/step) and A's global-load latency are
//   hidden by co-resident waves; 1.75x the wave pool should cut the
//   latency-exposed fraction. Cost: 4 phase iters (12 barriers/row vs 6) +
//   2x B-setup scans -- both small vs the hiding gain.
// R11 lessons kept: float2-packed bd_* (b64 LDS ops), branch-folded advance
// (e1c/e2c zeroed unless slider&&nfse; +0.0 add is bit-safe).
// R10 lesson: single-axis changes only. Slot-B + __syncthreads structure kept.
// Numerics: carry path bit-identical to numpy fp32 (contract off, IEEE
// div/sqrt, per-step rr = lk>192); outputs *1/512 pow2-exact, *1/384 <=1ulp
// output-only (absmax 0.0078 stable R8-R11).
// Frozen: plain stores (R2/R4), dense per-phase global access (R1),
// no VGPR squeeze (R5).

#define H 512
#define RPB 4      // rows per block = waves per block
#define HALF 128   // k-steps staged per phase
#define NPH (H / HALF)
#define JPP (HALF / 64)   // j-iterations per phase

typedef float v2f __attribute__((ext_vector_type(2)));

__global__ __launch_bounds__(256, 4)
void construct_map_seg(const float* __restrict__ mapvars,
                       const float* __restrict__ rel,
                       const float* __restrict__ start_pos,
                       const float* __restrict__ lmul,
                       const int* __restrict__ nfse_p,
                       float* __restrict__ out)
{
#pragma clang fp contract(off)
    __shared__ float s_lk[H];
    __shared__ float s_issl[H];
    __shared__ int   seg_list[H + 8];
    __shared__ int   nseg_s;
    __shared__ float2 bd_d [RPB][HALF];   // {dx, dy}
    __shared__ float2 bd_r [RPB][HALF];   // {rerand_x, rerand_y}
    __shared__ float2 bd_a [RPB][HALF];   // {e1c, e2c} advance (0 unless slider&&nfse)
    __shared__ float2 bd_xy[RPB][HALF];   // {_x, _y} result

    const int tid = threadIdx.x;
    const int w = tid >> 6;
    const int lane = tid & 63;
    const int row = blockIdx.x * RPB + w;

    const float lm = lmul[0];
    for (int i = tid; i < H; i += 256) {
        s_lk[i] = __fmul_rn(lm, rel[5 * H + i]);   // l = lmul * note_dist
        s_issl[i] = rel[i];                        // is_slider
    }
    __syncthreads();

    // segment list: starts = {0} U {k : l[k] > 192}  (k-only, all rows share)
    if (tid < 64) {
        int base = 0;
        for (int c = 0; c < H / 64; ++c) {
            int k = c * 64 + tid;
            bool isr = (k == 0) || (s_lk[k] > 192.0f);
            unsigned long long m = __ballot(isr);
            int idx = base + __popcll(m & ((1ull << tid) - 1ull));
            if (isr) seg_list[idx] = k;
            base += __popcll(m);
        }
        if (tid == 0) { seg_list[base] = H; nseg_s = base; }
    }
    __syncthreads();

    const int nseg = nseg_s;
    const bool nfse = (nfse_p[0] != 0);
    const float sx = start_pos[0], sy = start_pos[1];

    const float WL = (float)(0.05 * 512.0);
    const float WR = (float)(0.95 * 512.0);
    const float WT = (float)(0.05 * 384.0);
    const float WB = (float)(0.95 * 384.0);

    const float* rowp = mapvars + (size_t)row * (4 * H);
    float* orow = out + (size_t)row * (H * 6);

    float pxs0 = 0.f, pys0 = 0.f, pxs1 = 0.f, pys1 = 0.f;
    float pxs2 = 0.f, pys2 = 0.f, pxs3 = 0.f, pys3 = 0.f;

    for (int h = 0; h < NPH; ++h) {
        const int kb = h * HALF;
        float o2r[JPP], o3r[JPP], e1r[JPP], e2r[JPP];

        // ---- A: heavy per-k math, dense, all lanes active ----
#pragma unroll
        for (int j = 0; j < JPP; ++j) {
            const int kk = lane + 64 * j;
            const int k = kb + kk;
            float m0 = rowp[k];
            float m1 = rowp[H + k];
            float m2 = rowp[2 * H + k];
            float m3 = rowp[3 * H + k];
            float sln  = rel[H + k];
            float scos = rel[3 * H + k];
            float ssin = rel[4 * H + k];
            float lk  = s_lk[k];
            float isf = s_issl[k];

            float len1 = __fsqrt_rn(__fadd_rn(__fmul_rn(m0, m0), __fmul_rn(m2, m2)));
            float ck = __fdiv_rn(m0, len1);
            float sk = __fdiv_rn(m2, len1);
            float len2 = __fsqrt_rn(__fadd_rn(__fmul_rn(m1, m1), __fmul_rn(m3, m3)));
            float ck2 = __fdiv_rn(m1, len2);
            float sk2 = __fdiv_rn(m3, len2);

            float dx = __fmul_rn(lk, ck);
            float dy = __fmul_rn(lk, sk);
            float rx = __fadd_rn(256.0f, __fmul_rn(256.0f, m0));
            float ry = __fadd_rn(192.0f, __fmul_rn(192.0f, m2));
            float e1 = __fmul_rn(ck2, sln);
            float e2 = __fmul_rn(sk2, sln);
            bool rr  = lk > 192.0f;
            bool isl = isf != 0.0f;
            float oa = __fadd_rn(__fmul_rn(ck2, scos), -__fmul_rn(sk2, ssin));
            float ob = __fadd_rn(__fmul_rn(ck2, ssin),  __fmul_rn(sk2, scos));
            o2r[j] = isl ? oa : (rr ? ck2 : ck);
            o3r[j] = isl ? ob : (rr ? sk2 : sk);
            e1r[j] = e1; e2r[j] = e2;

            v2f d2 = {dx, dy};
            v2f r2 = {rx, ry};
            bool adv = isl && nfse;
            v2f a2 = {adv ? e1 : 0.0f, adv ? e2 : 0.0f};
            *(v2f*)&bd_d[w][kk] = d2;
            *(v2f*)&bd_r[w][kk] = r2;
            *(v2f*)&bd_a[w][kk] = a2;
        }
        __syncthreads();

        // ---- B: serial carry chain, slot-parallel (R9/R11 structure) ----
#pragma unroll
        for (int slot = 0; slot < 4; ++slot) {
            const int sid = lane + 64 * slot;
            if (sid < nseg) {
                const int k0 = seg_list[sid];
                const int k1 = seg_list[sid + 1];
                const int lo = (k0 > kb) ? k0 : kb;
                const int hi = (k1 < kb + HALF) ? k1 : (kb + HALF);
                float px, py;
                if (k0 >= kb) {              // segment starts in this phase
                    px = (k0 == 0) ? sx : 0.0f;
                    py = (k0 == 0) ? sy : 0.0f;
                } else {                     // continues from a previous phase
                    px = (slot == 0) ? pxs0 : (slot == 1) ? pxs1 : (slot == 2) ? pxs2 : pxs3;
                    py = (slot == 0) ? pys0 : (slot == 1) ? pys1 : (slot == 2) ? pys2 : pys3;
                }
                for (int k = lo; k < hi; ++k) {
                    const int kk = k - kb;
                    float lk = s_lk[k];
                    float _x, _y;
                    if (lk > 192.0f) {       // rerand: carry-independent
                        float2 r2 = bd_r[w][kk];
                        _x = r2.x;
                        _y = r2.y;
                    } else {
                        float2 d2 = bd_d[w][kk];
                        float hl = __fmul_rn(lk, 0.5f);
                        float wl = __fadd_rn(WL, hl);
                        float wr = __fadd_rn(WR, -hl);
                        float wt = __fadd_rn(WT, hl);
                        float wb = __fadd_rn(WB, -hl);
                        float dx = d2.x, dy = d2.y;
                        float adx = fabsf(dx), ady = fabsf(dy);
                        float xd = (px < wl) ? adx : ((px > wr) ? -adx : (((px > wl) && (px < wr)) ? dx : 0.0f));
                        float yd = (py < wt) ? ady : ((py > wb) ? -ady : (((py > wt) && (py < wb)) ? dy : 0.0f));
                        _x = __fadd_rn(px, xd);
                        _y = __fadd_rn(py, yd);
                    }
                    v2f xy = {_x, _y};
                    *(v2f*)&bd_xy[w][kk] = xy;
                    float2 a2 = bd_a[w][kk];     // {0,0} unless slider && nfse
                    px = __fadd_rn(_x, a2.x);    // +0.0 bit-safe
                    py = __fadd_rn(_y, a2.y);
                }
                // persist carry for segments crossing the phase boundary
                if (slot == 0) { pxs0 = px; pys0 = py; }
                else if (slot == 1) { pxs1 = px; pys1 = py; }
                else if (slot == 2) { pxs2 = px; pys2 = py; }
                else { pxs3 = px; pys3 = py; }
            }
        }
        __syncthreads();

        // ---- C: output assembly, dense stores ----
#pragma unroll
        for (int j = 0; j < JPP; ++j) {
            const int kk = lane + 64 * j;
            const int k = kb + kk;
            float2 xy = bd_xy[w][kk];
            float _x = xy.x, _y = xy.y;
            float o0 = __fmul_rn(_x, 1.0f / 512.0f);
            float o1 = __fmul_rn(_y, 1.0f / 384.0f);
            bool isl = s_issl[k] != 0.0f;
            float o4 = o0, o5 = o1;
            if (isl) {
                o4 = __fmul_rn(__fadd_rn(_x, e1r[j]), 1.0f / 512.0f);
                o5 = __fmul_rn(__fadd_rn(_y, e2r[j]), 1.0f / 384.0f);
            }
            float* op = orow + (size_t)k * 6;
            v2f a = {o0, o1};
            v2f b = {o2r[j], o3r[j]};
            v2f c = {o4, o5};
            *(v2f*)(op)     = a;
            *(v2f*)(op + 2) = b;
            *(v2f*)(op + 4) = c;
        }
        __syncthreads();
    }
}

extern "C" void kernel_launch(void* const* d_in, const int* in_sizes, int n_in,
                              void* d_out, int out_size, void* d_ws, size_t ws_size,
                              hipStream_t stream) {
    const float* mapvars = (const float*)d_in[0];
    const float* rel     = (const float*)d_in[1];
    const float* sp      = (const float*)d_in[2];
    const float* lm      = (const float*)d_in[3];
    const int*   nfse    = (const int*)d_in[4];
    float* out = (float*)d_out;

    const int B = in_sizes[0] / (4 * H);   // 32768
    hipLaunchKernelGGL(construct_map_seg, dim3(B / RPB), dim3(256), 0, stream,
                       mapvars, rel, sp, lm, nfse, out);
}

// Round 13
// 168.605 us; speedup vs baseline: 1.2416x; 1.0300x over previous
//
#include <hip/hip_runtime.h>

// KerasCustomMappingLayer: B=32768 rows x H=512 sequential steps, out (B,H,6) f32.
//
// R13 = R12 (proven 173.7us) with ONE change: branchless B + bd_r folded into bd_d.
//   - Every k with lk>192 is a segment HEAD (by construction of seg_list), so
//     bd_d's {dx,dy} slot is dead there; A writes {rx,ry} instead at heads.
//   - B computes the wall path unconditionally and selects via cndmask:
//     _x = head ? d2.x : px+xd  -- bit-identical to the old branch (both arms
//     are computed with the exact same ops; only the control flow changed).
//   - Removes the divergent if/else (both paths used to issue) ~30% B-issue cut,
//     one fewer LDS array read, and -4KB LDS: 22.6 -> ~18.1KB => 8 blocks/CU
//     (32 waves/CU = HW max, up from 7 blocks).
// R12 lesson kept: HALF=128 occupancy lever. R11: float2-packed bd_*,
// branch-folded advance (+0.0 bit-safe). R10: single-axis changes only.
// Numerics: carry path bit-identical to numpy fp32 (contract off, IEEE
// div/sqrt); outputs *1/512 pow2-exact, *1/384 <=1ulp output-only
// (absmax 0.0078125 stable R8-R12).
// Frozen: plain stores (R2/R4), dense per-phase global access (R1),
// no VGPR squeeze (R5: keep launch_bounds(256,4)).

#define H 512
#define RPB 4      // rows per block = waves per block
#define HALF 128   // k-steps staged per phase
#define NPH (H / HALF)
#define JPP (HALF / 64)   // j-iterations per phase

typedef float v2f __attribute__((ext_vector_type(2)));

__global__ __launch_bounds__(256, 4)
void construct_map_seg(const float* __restrict__ mapvars,
                       const float* __restrict__ rel,
                       const float* __restrict__ start_pos,
                       const float* __restrict__ lmul,
                       const int* __restrict__ nfse_p,
                       float* __restrict__ out)
{
#pragma clang fp contract(off)
    __shared__ float s_lk[H];
    __shared__ float s_issl[H];
    __shared__ int   seg_list[H + 8];
    __shared__ int   nseg_s;
    __shared__ float2 bd_d [RPB][HALF];   // {dx,dy}, or {rerand_x,rerand_y} at heads
    __shared__ float2 bd_a [RPB][HALF];   // {e1c, e2c} advance (0 unless slider&&nfse)
    __shared__ float2 bd_xy[RPB][HALF];   // {_x, _y} result

    const int tid = threadIdx.x;
    const int w = tid >> 6;
    const int lane = tid & 63;
    const int row = blockIdx.x * RPB + w;

    const float lm = lmul[0];
    for (int i = tid; i < H; i += 256) {
        s_lk[i] = __fmul_rn(lm, rel[5 * H + i]);   // l = lmul * note_dist
        s_issl[i] = rel[i];                        // is_slider
    }
    __syncthreads();

    // segment list: starts = {0} U {k : l[k] > 192}  (k-only, all rows share)
    if (tid < 64) {
        int base = 0;
        for (int c = 0; c < H / 64; ++c) {
            int k = c * 64 + tid;
            bool isr = (k == 0) || (s_lk[k] > 192.0f);
            unsigned long long m = __ballot(isr);
            int idx = base + __popcll(m & ((1ull << tid) - 1ull));
            if (isr) seg_list[idx] = k;
            base += __popcll(m);
        }
        if (tid == 0) { seg_list[base] = H; nseg_s = base; }
    }
    __syncthreads();

    const int nseg = nseg_s;
    const bool nfse = (nfse_p[0] != 0);
    const float sx = start_pos[0], sy = start_pos[1];

    const float WL = (float)(0.05 * 512.0);
    const float WR = (float)(0.95 * 512.0);
    const float WT = (float)(0.05 * 384.0);
    const float WB = (float)(0.95 * 384.0);

    const float* rowp = mapvars + (size_t)row * (4 * H);
    float* orow = out + (size_t)row * (H * 6);

    float pxs0 = 0.f, pys0 = 0.f, pxs1 = 0.f, pys1 = 0.f;
    float pxs2 = 0.f, pys2 = 0.f, pxs3 = 0.f, pys3 = 0.f;

    for (int h = 0; h < NPH; ++h) {
        const int kb = h * HALF;
        float o2r[JPP], o3r[JPP], e1r[JPP], e2r[JPP];

        // ---- A: heavy per-k math, dense, all lanes active ----
#pragma unroll
        for (int j = 0; j < JPP; ++j) {
            const int kk = lane + 64 * j;
            const int k = kb + kk;
            float m0 = rowp[k];
            float m1 = rowp[H + k];
            float m2 = rowp[2 * H + k];
            float m3 = rowp[3 * H + k];
            float sln  = rel[H + k];
            float scos = rel[3 * H + k];
            float ssin = rel[4 * H + k];
            float lk  = s_lk[k];
            float isf = s_issl[k];

            float len1 = __fsqrt_rn(__fadd_rn(__fmul_rn(m0, m0), __fmul_rn(m2, m2)));
            float ck = __fdiv_rn(m0, len1);
            float sk = __fdiv_rn(m2, len1);
            float len2 = __fsqrt_rn(__fadd_rn(__fmul_rn(m1, m1), __fmul_rn(m3, m3)));
            float ck2 = __fdiv_rn(m1, len2);
            float sk2 = __fdiv_rn(m3, len2);

            float dx = __fmul_rn(lk, ck);
            float dy = __fmul_rn(lk, sk);
            float rx = __fadd_rn(256.0f, __fmul_rn(256.0f, m0));
            float ry = __fadd_rn(192.0f, __fmul_rn(192.0f, m2));
            float e1 = __fmul_rn(ck2, sln);
            float e2 = __fmul_rn(sk2, sln);
            bool rr  = lk > 192.0f;                 // == "segment head" position
            bool isl = isf != 0.0f;
            float oa = __fadd_rn(__fmul_rn(ck2, scos), -__fmul_rn(sk2, ssin));
            float ob = __fadd_rn(__fmul_rn(ck2, ssin),  __fmul_rn(sk2, scos));
            o2r[j] = isl ? oa : (rr ? ck2 : ck);
            o3r[j] = isl ? ob : (rr ? sk2 : sk);
            e1r[j] = e1; e2r[j] = e2;

            // head positions carry {rx,ry}; dx/dy are dead there (B selects)
            v2f d2 = {rr ? rx : dx, rr ? ry : dy};
            bool adv = isl && nfse;
            v2f a2 = {adv ? e1 : 0.0f, adv ? e2 : 0.0f};
            *(v2f*)&bd_d[w][kk] = d2;
            *(v2f*)&bd_a[w][kk] = a2;
        }
        __syncthreads();

        // ---- B: serial carry chain, slot-parallel, BRANCHLESS steps ----
#pragma unroll
        for (int slot = 0; slot < 4; ++slot) {
            const int sid = lane + 64 * slot;
            if (sid < nseg) {
                const int k0 = seg_list[sid];
                const int k1 = seg_list[sid + 1];
                const int lo = (k0 > kb) ? k0 : kb;
                const int hi = (k1 < kb + HALF) ? k1 : (kb + HALF);
                float px, py;
                if (k0 >= kb) {              // segment starts in this phase
                    px = (k0 == 0) ? sx : 0.0f;
                    py = (k0 == 0) ? sy : 0.0f;
                } else {                     // continues from a previous phase
                    px = (slot == 0) ? pxs0 : (slot == 1) ? pxs1 : (slot == 2) ? pxs2 : pxs3;
                    py = (slot == 0) ? pys0 : (slot == 1) ? pys1 : (slot == 2) ? pys2 : pys3;
                }
                for (int k = lo; k < hi; ++k) {
                    const int kk = k - kb;
                    float lk = s_lk[k];
                    float2 d2 = bd_d[w][kk];         // {dx,dy} or {rx,ry}@head
                    bool head = lk > 192.0f;
                    float hl = __fmul_rn(lk, 0.5f);
                    float wl = __fadd_rn(WL, hl);
                    float wr = __fadd_rn(WR, -hl);
                    float wt = __fadd_rn(WT, hl);
                    float wb = __fadd_rn(WB, -hl);
                    float dx = d2.x, dy = d2.y;
                    float adx = fabsf(dx), ady = fabsf(dy);
                    float xd = (px < wl) ? adx : ((px > wr) ? -adx : (((px > wl) && (px < wr)) ? dx : 0.0f));
                    float yd = (py < wt) ? ady : ((py > wb) ? -ady : (((py > wt) && (py < wb)) ? dy : 0.0f));
                    float _x = head ? d2.x : __fadd_rn(px, xd);
                    float _y = head ? d2.y : __fadd_rn(py, yd);
                    v2f xy = {_x, _y};
                    *(v2f*)&bd_xy[w][kk] = xy;
                    float2 a2 = bd_a[w][kk];         // {0,0} unless slider && nfse
                    px = __fadd_rn(_x, a2.x);        // +0.0 bit-safe
                    py = __fadd_rn(_y, a2.y);
                }
                // persist carry for segments crossing the phase boundary
                if (slot == 0) { pxs0 = px; pys0 = py; }
                else if (slot == 1) { pxs1 = px; pys1 = py; }
                else if (slot == 2) { pxs2 = px; pys2 = py; }
                else { pxs3 = px; pys3 = py; }
            }
        }
        __syncthreads();

        // ---- C: output assembly, dense stores ----
#pragma unroll
        for (int j = 0; j < JPP; ++j) {
            const int kk = lane + 64 * j;
            const int k = kb + kk;
            float2 xy = bd_xy[w][kk];
            float _x = xy.x, _y = xy.y;
            float o0 = __fmul_rn(_x, 1.0f / 512.0f);
            float o1 = __fmul_rn(_y, 1.0f / 384.0f);
            bool isl = s_issl[k] != 0.0f;
            float o4 = o0, o5 = o1;
            if (isl) {
                o4 = __fmul_rn(__fadd_rn(_x, e1r[j]), 1.0f / 512.0f);
                o5 = __fmul_rn(__fadd_rn(_y, e2r[j]), 1.0f / 384.0f);
            }
            float* op = orow + (size_t)k * 6;
            v2f a = {o0, o1};
            v2f b = {o2r[j], o3r[j]};
            v2f c = {o4, o5};
            *(v2f*)(op)     = a;
            *(v2f*)(op + 2) = b;
            *(v2f*)(op + 4) = c;
        }
        __syncthreads();
    }
}

extern "C" void kernel_launch(void* const* d_in, const int* in_sizes, int n_in,
                              void* d_out, int out_size, void* d_ws, size_t ws_size,
                              hipStream_t stream) {
    const float* mapvars = (const float*)d_in[0];
    const float* rel     = (const float*)d_in[1];
    const float* sp      = (const float*)d_in[2];
    const float* lm      = (const float*)d_in[3];
    const int*   nfse    = (const int*)d_in[4];
    float* out = (float*)d_out;

    const int B = in_sizes[0] / (4 * H);   // 32768
    hipLaunchKernelGGL(construct_map_seg, dim3(B / RPB), dim3(256), 0, stream,
                       mapvars, rel, sp, lm, nfse, out);
}

// Round 14
// 151.974 us; speedup vs baseline: 1.3775x; 1.1094x over previous
//
#include <hip/hip_runtime.h>
#include <math.h>

// KerasCustomMappingLayer: B=32768 rows x H=512 sequential steps, out (B,H,6) f32.
//
// R14 = R13 (proven 168.6us) with the B phase overhauled (single subsystem):
//  (1) block-shared per-phase wall table s_w[kk*2+par] = {wlo,whi}, heads
//      encoded as {-inf,+inf} so the cd-select returns d unconditionally at
//      heads; with fresh-segment carry p==0, _c = 0 + r == r bit-exactly
//      (k==0 handled by head0: p init 0 iff l[0]>192).
//  (2) x/y PAIR-SPLIT: lane parity owns one chain (chains are independent
//      given dx/dy). Per-step: 2 ds_read_b64 + 1 ds_write_b32 + ~12 VALU
//      ~= 19 instr vs R13's ~38. Serial round count unchanged: per-phase
//      REBASED slot index li = sid - S_h keeps the ~31 active segments in
//      one 32-pair slot; S_h binary-searched once at seg_list build.
//  (3) phase-crossing carry via per-wave LDS bd_h[w][par] (unique
//      writer = segment containing phase end; unique reader = li==0 pair;
//      existing __syncthreads orders the phases).
//  s_issl dropped from LDS (A/C read rel[k] from L2). LDS ~18.1KB -> 8 blocks/CU.
// Numerics: carry path bit-identical to numpy fp32 (contract off, IEEE
// div/sqrt; wall adds blo+hl / bhi-hl identical ops, now computed once per
// block instead of per row). Outputs *1/512 pow2-exact, *1/384 <=1ulp
// output-only (absmax 0.0078125 stable R8-R13).
// Frozen: plain stores (R2/R4), dense per-phase global access (R1),
// no VGPR squeeze (R5), HALF=128 (R12), single-axis change (R10).

#define H 512
#define RPB 4      // rows per block = waves per block
#define HALF 128   // k-steps staged per phase
#define NPH (H / HALF)
#define JPP (HALF / 64)   // j-iterations per phase
#define SLOTS 5    // 5*32 pairs = 160 >= max 129 segments intersecting a phase

typedef float v2f __attribute__((ext_vector_type(2)));
typedef float v4f __attribute__((ext_vector_type(4)));

__global__ __launch_bounds__(256, 4)
void construct_map_seg(const float* __restrict__ mapvars,
                       const float* __restrict__ rel,
                       const float* __restrict__ start_pos,
                       const float* __restrict__ lmul,
                       const int* __restrict__ nfse_p,
                       float* __restrict__ out)
{
#pragma clang fp contract(off)
    __shared__ float s_lk[H];
    __shared__ int   seg_list[H + 8];
    __shared__ int   nseg_s;
    __shared__ int   s_S[NPH];            // first segment intersecting each phase
    __shared__ float2 s_w[HALF * 2];      // block-shared: {wlo,whi} per (kk,par); heads {-inf,+inf}
    __shared__ float2 bd_pk[RPB][HALF * 2]; // per-wave: {d_or_r, advance} per (kk,par)
    __shared__ float2 bd_xy[RPB][HALF];   // {_x,_y} results
    __shared__ float  bd_h[RPB][2];       // phase-crossing carry per chain

    const int tid = threadIdx.x;
    const int w = tid >> 6;
    const int lane = tid & 63;
    const int pair = lane >> 1;
    const int par = lane & 1;
    const int row = blockIdx.x * RPB + w;

    const float lm = lmul[0];
    for (int i = tid; i < H; i += 256)
        s_lk[i] = __fmul_rn(lm, rel[5 * H + i]);   // l = lmul * note_dist
    __syncthreads();

    // segment list: starts = {0} U {k : l[k] > 192}  (k-only, all rows share)
    if (tid < 64) {
        int base = 0;
        for (int c = 0; c < H / 64; ++c) {
            int k = c * 64 + tid;
            bool isr = (k == 0) || (s_lk[k] > 192.0f);
            unsigned long long m = __ballot(isr);
            int idx = base + __popcll(m & ((1ull << tid) - 1ull));
            if (isr) seg_list[idx] = k;
            base += __popcll(m);
        }
        if (tid == 0) { seg_list[base] = H; nseg_s = base; }
        // per-phase first-intersecting segment: S_h = (first idx > kb) - 1
        if (tid < NPH) {
            int kb = tid * HALF;
            int lo = 0, hi = base + 1;                 // search idx range [0, nseg]
            while (lo < hi) { int m = (lo + hi) >> 1; if (seg_list[m] <= kb) lo = m + 1; else hi = m; }
            s_S[tid] = lo - 1;                         // seg_list[0]=0 => S>=0
        }
    }
    __syncthreads();

    const int nseg = nseg_s;
    const bool nfse = (nfse_p[0] != 0);
    const float sx = start_pos[0], sy = start_pos[1];

    const float WL = (float)(0.05 * 512.0);
    const float WR = (float)(0.95 * 512.0);
    const float WT = (float)(0.05 * 384.0);
    const float WB = (float)(0.95 * 384.0);

    // fresh-segment init for k==0: start_pos unless k==0 is itself a rerand head
    const bool head0 = s_lk[0] > 192.0f;
    const float pinit0 = head0 ? 0.0f : (par ? sy : sx);

    const float* rowp = mapvars + (size_t)row * (4 * H);
    float* orow = out + (size_t)row * (H * 6);

    for (int h = 0; h < NPH; ++h) {
        const int kb = h * HALF;
        const int kend = kb + HALF;
        float o2r[JPP], o3r[JPP], e1r[JPP], e2r[JPP];

        // ---- wall table for this phase (block-shared, row-independent) ----
        {
            const int i = tid;                 // 256 threads == HALF*2 entries
            const int kkw = i >> 1, prw = i & 1;
            float lk = s_lk[kb + kkw];
            bool head = lk > 192.0f;
            float hl = __fmul_rn(lk, 0.5f);
            float blo = prw ? WT : WL;
            float bhi = prw ? WB : WR;
            v2f w2 = {head ? -INFINITY : __fadd_rn(blo, hl),
                      head ?  INFINITY : __fadd_rn(bhi, -hl)};
            *(v2f*)&s_w[i] = w2;
        }

        // ---- A: heavy per-k math, dense, all lanes active ----
#pragma unroll
        for (int j = 0; j < JPP; ++j) {
            const int kk = lane + 64 * j;
            const int k = kb + kk;
            float m0 = rowp[k];
            float m1 = rowp[H + k];
            float m2 = rowp[2 * H + k];
            float m3 = rowp[3 * H + k];
            float sln  = rel[H + k];
            float scos = rel[3 * H + k];
            float ssin = rel[4 * H + k];
            float lk  = s_lk[k];
            float isf = rel[k];                       // is_slider (L2-broadcast)

            float len1 = __fsqrt_rn(__fadd_rn(__fmul_rn(m0, m0), __fmul_rn(m2, m2)));
            float ck = __fdiv_rn(m0, len1);
            float sk = __fdiv_rn(m2, len1);
            float len2 = __fsqrt_rn(__fadd_rn(__fmul_rn(m1, m1), __fmul_rn(m3, m3)));
            float ck2 = __fdiv_rn(m1, len2);
            float sk2 = __fdiv_rn(m3, len2);

            float dx = __fmul_rn(lk, ck);
            float dy = __fmul_rn(lk, sk);
            float rx = __fadd_rn(256.0f, __fmul_rn(256.0f, m0));
            float ry = __fadd_rn(192.0f, __fmul_rn(192.0f, m2));
            float e1 = __fmul_rn(ck2, sln);
            float e2 = __fmul_rn(ck2, 0.0f);          // placeholder (overwritten below)
            e2 = __fmul_rn(sk2, sln);
            bool rr  = lk > 192.0f;                   // head position
            bool isl = isf != 0.0f;
            float oa = __fadd_rn(__fmul_rn(ck2, scos), -__fmul_rn(sk2, ssin));
            float ob = __fadd_rn(__fmul_rn(ck2, ssin),  __fmul_rn(sk2, scos));
            o2r[j] = isl ? oa : (rr ? ck2 : ck);
            o3r[j] = isl ? ob : (rr ? sk2 : sk);
            e1r[j] = e1; e2r[j] = e2;

            bool adv = isl && nfse;
            v4f pk4 = {rr ? rx : dx, adv ? e1 : 0.0f,
                       rr ? ry : dy, adv ? e2 : 0.0f};
            *(v4f*)&bd_pk[w][2 * kk] = pk4;           // one b128 store
        }
        __syncthreads();

        // ---- B: serial carry chain, pair-split (lane parity = chain) ----
        {
            const int S = s_S[h];
#pragma unroll
            for (int slot = 0; slot < SLOTS; ++slot) {
                const int sid = S + pair + 32 * slot;
                if (sid < nseg) {
                    const int k0 = seg_list[sid];
                    const int k1 = seg_list[sid + 1];
                    const int lo = (k0 > kb) ? k0 : kb;
                    const int hi = (k1 < kend) ? k1 : kend;
                    if (lo < hi) {
                        float p;
                        if (k0 < kb)      p = bd_h[w][par];     // crossing-in (li==0 only)
                        else if (k0 == 0) p = pinit0;
                        else              p = 0.0f;             // fresh head segment
                        for (int k = lo; k < hi; ++k) {
                            const int kk = k - kb;
                            float2 w2 = s_w[2 * kk + par];
                            float2 pk = bd_pk[w][2 * kk + par];
                            float d = pk.x, a = pk.y;
                            float ad = fabsf(d);
                            float cd = (p < w2.x) ? ad
                                     : ((p > w2.y) ? -ad
                                     : (((p > w2.x) && (p < w2.y)) ? d : 0.0f));
                            float _c = __fadd_rn(p, cd);        // head: 0 + r = r
                            ((float*)&bd_xy[w][kk])[par] = _c;
                            p = __fadd_rn(_c, a);               // +0.0 bit-safe
                        }
                        if (k1 > kend) bd_h[w][par] = p;        // crossing-out (unique)
                    }
                }
            }
        }
        __syncthreads();

        // ---- C: output assembly, dense stores ----
#pragma unroll
        for (int j = 0; j < JPP; ++j) {
            const int kk = lane + 64 * j;
            const int k = kb + kk;
            float2 xy = bd_xy[w][kk];
            float _x = xy.x, _y = xy.y;
            float o0 = __fmul_rn(_x, 1.0f / 512.0f);
            float o1 = __fmul_rn(_y, 1.0f / 384.0f);
            bool isl = rel[k] != 0.0f;
            float o4 = o0, o5 = o1;
            if (isl) {
                o4 = __fmul_rn(__fadd_rn(_x, e1r[j]), 1.0f / 512.0f);
                o5 = __fmul_rn(__fadd_rn(_y, e2r[j]), 1.0f / 384.0f);
            }
            float* op = orow + (size_t)k * 6;
            v2f a = {o0, o1};
            v2f b = {o2r[j], o3r[j]};
            v2f c = {o4, o5};
            *(v2f*)(op)     = a;
            *(v2f*)(op + 2) = b;
            *(v2f*)(op + 4) = c;
        }
        __syncthreads();
    }
}

extern "C" void kernel_launch(void* const* d_in, const int* in_sizes, int n_in,
                              void* d_out, int out_size, void* d_ws, size_t ws_size,
                              hipStream_t stream) {
    const float* mapvars = (const float*)d_in[0];
    const float* rel     = (const float*)d_in[1];
    const float* sp      = (const float*)d_in[2];
    const float* lm      = (const float*)d_in[3];
    const int*   nfse    = (const int*)d_in[4];
    float* out = (float*)d_out;

    const int B = in_sizes[0] / (4 * H);   // 32768
    hipLaunchKernelGGL(construct_map_seg, dim3(B / RPB), dim3(256), 0, stream,
                       mapvars, rel, sp, lm, nfse, out);
}